// Round 3
// baseline (819.272 us; speedup 1.0000x reference)
//
#include <hip/hip_runtime.h>
#include <hip/hip_bf16.h>
#include <stdint.h>

#define M_TIME 64
#define N_DICT 20000
#define B_VOX  8192

#define NTILES 313    // ceil(20000/64); last tile padded with zeros

typedef _Float16 v8h __attribute__((ext_vector_type(8)));   // 8 f16 (4 VGPRs)
typedef float    v4f __attribute__((ext_vector_type(4)));
typedef float    v2f __attribute__((ext_vector_type(2)));
typedef __attribute__((address_space(3))) unsigned int  lds_u32;
typedef const __attribute__((address_space(1))) unsigned int glb_u32;

__device__ __forceinline__ unsigned long long u64max(unsigned long long a, unsigned long long b) { return a > b ? a : b; }
__device__ __forceinline__ unsigned umin32(unsigned a, unsigned b) { return a < b ? a : b; }
__device__ __forceinline__ unsigned umax32(unsigned a, unsigned b) { return a > b ? a : b; }
// median of 3 == second-largest of 3: one VOP3 op (pure reg computation).
__device__ __forceinline__ unsigned umed3(unsigned a, unsigned b, unsigned c) {
    unsigned d;
    asm("v_med3_u32 %0, %1, %2, %3" : "=v"(d) : "v"(a), "v"(b), "v"(c));
    return d;
}

// ---------------------------------------------------------------------------
// Prepass: convert y to f16 ONCE, packed in A-fragment order.
// Tile T = 16 fragment-rows fr = (arr*2 + h)*4 + quad; row = 64 n x 8 f16
// (k = h*32 + quad*8 + j). 16 KB/tile.
// ---------------------------------------------------------------------------
__global__ __launch_bounds__(256) void split_y(
    const float* __restrict__ yr, const float* __restrict__ yi,
    v8h* __restrict__ yp)
{
    const int u = blockIdx.x * 256 + threadIdx.x;   // [arr][T][j(8)][n_l(64)]
    const int n_l = u & 63;
    const int j   = (u >> 6) & 7;       // fragment sub-row: k = j*8 .. j*8+7
    const int T   = (u >> 9) % NTILES;
    const int arr = u / (NTILES * 512);
    if (arr > 1) return;
    const float* P = arr ? yi : yr;
    const int n_g = T * 64 + n_l;
    v8h V;
#pragma unroll
    for (int c = 0; c < 8; ++c) {
        float v = 0.f;
        if (n_g < N_DICT) v = P[(j * 8 + c) * N_DICT + n_g];
        V[c] = (_Float16)v;
    }
    const int fr = (arr * 2 + (j >> 2)) * 4 + (j & 3);   // h = j>>2, quad = j&3
    yp[((size_t)T * 16 + fr) * 64 + n_l] = V;
}

// ---------------------------------------------------------------------------
// Phase A: f16 1-term MFMA GEMM + per-chunk top-2 (u32 packed comparator).
// R17: packed-f32 sim (v_pk_fma) + v_med3_u32 second-best (~4.5 VALU/elem).
// R19: 512-thread blocks (8 waves) over 128 voxels, SAME 2x16KB LDS tile
// buffers — LDS/block amortized over 2x the waves. 4 blocks/CU x 8 waves
// = 32 waves/CU (vs 12 measured at 256-thread blocks); the per-tile
// vmcnt(0)+barrier drain now hides under 3 other resident blocks.
// R18's counted-vmcnt 3-buffer ring REVERTED: it cost occupancy (LDS
// 48.5 KB -> 3 blocks/CU, Occ 38->29%) and MfmaUtil dropped — compiler's
// own 2-buffer schedule + wave-level overlap wins (guide m99/m131-m140).
// __launch_bounds__(512,8): VGPR cap 64; R1 measured 56 for this body.
// ---------------------------------------------------------------------------
__global__ __launch_bounds__(512, 8) void gemm_pre(
    const float* __restrict__ ir, const float* __restrict__ ii,
    const v8h* __restrict__ yp,
    unsigned* __restrict__ cand, int tpc, int slots)
{
    __shared__ float4 ys4[2][1024];         // 2 x 16 KB ping-pong
    __shared__ unsigned xm[4][2][16][2];    // [wb][bt][col][a1,a2]

    const int tid  = threadIdx.x;
    const int wave = tid >> 6, lane = tid & 63;
    const int quad = lane >> 4, col = lane & 15;
    const int wb   = wave >> 1, wn = wave & 1;          // wb 0..3
    const int vox_w = blockIdx.x * 128 + wb * 32;
    const int chunk = blockIdx.y;
    const int T0 = chunk * tpc;
    const int T1 = (T0 + tpc < NTILES) ? T0 + tpc : NTILES;

    auto dma_tile = [&](int T, int buf) {
        const float4* src = (const float4*)((const char*)yp + (size_t)T * 16384);
#pragma unroll
        for (int p = 0; p < 2; ++p) {                   // 512 thr x 2 = 1024 float4
            const int base = p * 512 + wave * 64;       // wave-uniform
            __builtin_amdgcn_global_load_lds(
                (glb_u32*)(src + base + lane),
                (lds_u32*)(&ys4[buf][base]), 16, 0, 0);
        }
    };

    // ---- prologue: DMA tile T0 into buffer 0 ----
    dma_tile(T0, 0);

    // ---- persistent input B-frags: [arr][bt][h] single f16 (RNE) ----
    v8h fh[2][2][2];
#pragma unroll
    for (int arr = 0; arr < 2; ++arr) {
        const float* P = arr ? ii : ir;
#pragma unroll
        for (int bt = 0; bt < 2; ++bt) {
            const int b = vox_w + bt * 16 + col;
#pragma unroll
            for (int h = 0; h < 2; ++h) {
                v8h H;
#pragma unroll
                for (int j = 0; j < 8; ++j) {
                    const int k = h * 32 + quad * 8 + j;
                    H[j] = (_Float16)P[k * B_VOX + b];
                }
                fh[arr][bt][h] = H;
            }
        }
    }

    const v4f zc = {0.f, 0.f, 0.f, 0.f};
    unsigned t2a[2] = {0u, 0u}, t2b[2] = {0u, 0u};

    for (int T = T0; T < T1; ++T) {
        const int par = (T - T0) & 1;
        __syncthreads();   // drains DMA(T) into buf[par]; buf[par^1] now free
        if (T + 1 < T1) dma_tile(T + 1, par ^ 1);
        const v8h* yv = (const v8h*)ys4[par];

        v4f acc[2][2][4];                       // [bt][nt][rr,ri,s1,s2]
#pragma unroll
        for (int h = 0; h < 2; ++h) {
#pragma unroll
            for (int nt = 0; nt < 2; ++nt) {
                const int nrow = (wn * 2 + nt) * 16 + col;
                const v8h yfr = yv[((0 * 2 + h) * 4 + quad) * 64 + nrow];  // yr frag
                const v8h yfi = yv[((1 * 2 + h) * 4 + quad) * 64 + nrow];  // yi frag
#pragma unroll
                for (int bt = 0; bt < 2; ++bt) {
#define MF(A, B, C) __builtin_amdgcn_mfma_f32_16x16x32_f16(A, B, C, 0, 0, 0)
                    if (h == 0) {               // first k-half: C = zero (no init movs)
                        acc[bt][nt][0] = MF(yfr, fh[0][bt][0], zc);
                        acc[bt][nt][1] = MF(yfi, fh[0][bt][0], zc);
                        acc[bt][nt][2] = MF(yfr, fh[1][bt][0], zc);
                        acc[bt][nt][3] = MF(yfi, fh[1][bt][0], zc);
                    } else {
                        acc[bt][nt][0] = MF(yfr, fh[0][bt][1], acc[bt][nt][0]);
                        acc[bt][nt][1] = MF(yfi, fh[0][bt][1], acc[bt][nt][1]);
                        acc[bt][nt][2] = MF(yfr, fh[1][bt][1], acc[bt][nt][2]);
                        acc[bt][nt][3] = MF(yfi, fh[1][bt][1], acc[bt][nt][3]);
                    }
#undef MF
                }
            }
        }

        // ---- sim + top-2: packed-f32 sim, med3 second-best ----
        const int tl = T - T0;
#pragma unroll
        for (int nt = 0; nt < 2; ++nt) {
            const unsigned base = 0x1FFFu
                - (unsigned)(tl * 64 + (wn * 2 + nt) * 16 + quad * 4);
            v2f s01[2], s23[2];
#pragma unroll
            for (int bt = 0; bt < 2; ++bt) {
                const v4f a0 = acc[bt][nt][0], a1 = acc[bt][nt][1];
                const v4f a2 = acc[bt][nt][2], a3 = acc[bt][nt][3];
                {
                    const v2f p0 = __builtin_shufflevector(a0, a0, 0, 1);
                    const v2f p1 = __builtin_shufflevector(a1, a1, 0, 1);
                    const v2f p2 = __builtin_shufflevector(a2, a2, 0, 1);
                    const v2f p3 = __builtin_shufflevector(a3, a3, 0, 1);
                    v2f s = p0 * p0;
                    s = __builtin_elementwise_fma(p1, p1, s);
                    s = __builtin_elementwise_fma(p2, p2, s);
                    s = __builtin_elementwise_fma(p3, p3, s);
                    s01[bt] = s;
                }
                {
                    const v2f p0 = __builtin_shufflevector(a0, a0, 2, 3);
                    const v2f p1 = __builtin_shufflevector(a1, a1, 2, 3);
                    const v2f p2 = __builtin_shufflevector(a2, a2, 2, 3);
                    const v2f p3 = __builtin_shufflevector(a3, a3, 2, 3);
                    v2f s = p0 * p0;
                    s = __builtin_elementwise_fma(p1, p1, s);
                    s = __builtin_elementwise_fma(p2, p2, s);
                    s = __builtin_elementwise_fma(p3, p3, s);
                    s23[bt] = s;
                }
            }
#pragma unroll
            for (int r = 0; r < 4; ++r) {
#pragma unroll
                for (int bt = 0; bt < 2; ++bt) {     // two bt chains interleave
                    const float s = (r < 2) ? s01[bt][r] : s23[bt][r - 2];
                    const unsigned pb = (__float_as_uint(s) & 0xFFFFE000u)
                                      | (base - (unsigned)r);
                    const unsigned nb = umed3(pb, t2a[bt], t2b[bt]);  // 2nd-best
                    t2a[bt] = umax32(pb, t2a[bt]);
                    t2b[bt] = nb;
                }
            }
        }
    }

    // ---- cross-lane top-2 merge over quads (lanes c, c+16, c+32, c+48) ----
    unsigned fa1[2], fa2[2];
#pragma unroll
    for (int bt = 0; bt < 2; ++bt) {
        unsigned a1 = t2a[bt], a2 = t2b[bt];
#pragma unroll
        for (int d = 16; d <= 32; d <<= 1) {
            unsigned b1 = (unsigned)__shfl_xor((int)a1, d, 64);
            unsigned b2 = (unsigned)__shfl_xor((int)a2, d, 64);
            unsigned mn = umin32(a1, b1);
            a1 = umax32(a1, b1);
            a2 = umax32(mn, umax32(a2, b2));
        }
        fa1[bt] = a1; fa2[bt] = a2;
    }
    // ---- cross-wave (wn) merge: wn==1 publishes, wn==0 writes ----
    __syncthreads();
    if (wn == 1 && lane < 16) {
#pragma unroll
        for (int bt = 0; bt < 2; ++bt) { xm[wb][bt][lane][0] = fa1[bt]; xm[wb][bt][lane][1] = fa2[bt]; }
    }
    __syncthreads();
    if (wn == 0 && lane < 16) {
#pragma unroll
        for (int bt = 0; bt < 2; ++bt) {
            unsigned b1 = xm[wb][bt][lane][0];
            unsigned b2 = xm[wb][bt][lane][1];
            unsigned m1 = umax32(fa1[bt], b1);
            unsigned m2 = umax32(umin32(fa1[bt], b1), umax32(fa2[bt], b2));
            const size_t vox = vox_w + bt * 16 + lane;
            cand[vox * slots + chunk * 2 + 0] = m1;
            cand[vox * slots + chunk * 2 + 1] = m2;
        }
    }
}

// ---------------------------------------------------------------------------
// Phase B (fused): exact fp32 rescore of candidates within 3% of approx max,
// winner lane computes scales and writes the 4 output rows directly.
// One wave per voxel.
// ---------------------------------------------------------------------------
__global__ __launch_bounds__(256) void rescore_finish(
    const float* __restrict__ ir, const float* __restrict__ ii,
    const float* __restrict__ yr, const float* __restrict__ yi,
    const float* __restrict__ inv, const float* __restrict__ x1,
    const float* __restrict__ x2,
    const unsigned* __restrict__ cand, int slots, int tpc,
    float* __restrict__ out)
{
    const int tid  = threadIdx.x;
    const int vox  = blockIdx.x * 4 + (tid >> 6);
    const int slot = tid & 63;

    unsigned p = (slot < slots) ? cand[(size_t)vox * slots + slot] : 0u;
    float sa = __uint_as_float(p & 0xFFFFE000u);
    const int chunkc = slot >> 1;
    const int nn = chunkc * tpc * 64 + (0x1FFF - (int)(p & 0x1FFFu));

    float amax = sa;
#pragma unroll
    for (int d = 1; d <= 32; d <<= 1) amax = fmaxf(amax, __shfl_xor(amax, d, 64));

    unsigned long long q = 0ull;
    float rr = 0.f, ri = 0.f, s1 = 0.f, s2 = 0.f;
    const bool active = (slot < slots) && (nn >= 0) && (nn < N_DICT)
                     && (sa >= 0.97f * amax);    // margin covers 1-term f16 error
    if (active) {
        for (int m = 0; m < M_TIME; ++m) {
            float a  = yr[(size_t)m * N_DICT + nn];
            float c  = yi[(size_t)m * N_DICT + nn];
            float vr = ir[m * B_VOX + vox];
            float vi = ii[m * B_VOX + vox];
            rr = fmaf(vr, a, rr); ri = fmaf(vr, c, ri);
            s1 = fmaf(vi, a, s1); s2 = fmaf(vi, c, s2);
        }
        float s = fmaf(rr, rr, fmaf(ri, ri, fmaf(s1, s1, s2 * s2)));
        q = (((unsigned long long)__float_as_uint(s)) << 32)
          | (unsigned long long)(0xFFFFFFFFu - (unsigned)nn);  // ties -> smaller n
    }
    unsigned long long qm = q;
#pragma unroll
    for (int d = 1; d <= 32; d <<= 1) qm = u64max(qm, __shfl_xor(qm, d, 64));

    if (active && q == qm && qm != 0ull) {       // exactly one lane (n in key)
        float ss = inv[nn];
        out[0 * B_VOX + vox] = (rr + s2) * ss;   // sum(yr*ir + yi*ii) * inv
        out[1 * B_VOX + vox] = (s1 - ri) * ss;   // sum(yr*ii - yi*ir) * inv
        out[2 * B_VOX + vox] = x1[nn];
        out[3 * B_VOX + vox] = x2[nn];
    }
}

// ---------------------------------------------------------------------------
// Last-resort fallbacks (tiny ws): fp32 brute-force argmax + finish.
// ---------------------------------------------------------------------------
__global__ __launch_bounds__(256, 3) void argmax_naive(
    const float* __restrict__ ir, const float* __restrict__ ii,
    const float* __restrict__ yr, const float* __restrict__ yi,
    int* __restrict__ idxout)
{
    int b = blockIdx.x * 256 + threadIdx.x;
    float bs = -1.0f; int bn = 0;
    for (int n = 0; n < N_DICT; ++n) {
        float a_rr = 0.f, a_ri = 0.f, a_s1 = 0.f, a_s2 = 0.f;
        for (int m = 0; m < M_TIME; ++m) {
            float a = yr[m * N_DICT + n], c = yi[m * N_DICT + n];
            float vr = ir[m * B_VOX + b], vi = ii[m * B_VOX + b];
            a_rr = fmaf(vr, a, a_rr); a_ri = fmaf(vr, c, a_ri);
            a_s1 = fmaf(vi, a, a_s1); a_s2 = fmaf(vi, c, a_s2);
        }
        float sim = fmaf(a_rr, a_rr, fmaf(a_ri, a_ri, fmaf(a_s1, a_s1, a_s2 * a_s2)));
        if (sim > bs) { bs = sim; bn = n; }
    }
    idxout[b] = bn;
}

__global__ void finish_k(const float* __restrict__ ir, const float* __restrict__ ii,
                         const float* __restrict__ yr, const float* __restrict__ yi,
                         const float* __restrict__ inv, const float* __restrict__ x1,
                         const float* __restrict__ x2,
                         const int* __restrict__ idxin, float* __restrict__ out)
{
    int b = blockIdx.x * blockDim.x + threadIdx.x;
    int idx = idxin[b];
    float ar = 0.f, ai = 0.f;
    for (int m = 0; m < M_TIME; ++m) {
        float a  = yr[(size_t)m * N_DICT + idx];
        float c  = yi[(size_t)m * N_DICT + idx];
        float vr = ir[m * B_VOX + b];
        float vi = ii[m * B_VOX + b];
        ar = fmaf(a, vr, ar); ar = fmaf(c, vi, ar);
        ai = fmaf(a, vi, ai); ai = fmaf(-c, vr, ai);
    }
    float s = inv[idx];
    out[0 * B_VOX + b] = ar * s;
    out[1 * B_VOX + b] = ai * s;
    out[2 * B_VOX + b] = x1[idx];
    out[3 * B_VOX + b] = x2[idx];
}

extern "C" void kernel_launch(void* const* d_in, const int* in_sizes, int n_in,
                              void* d_out, int out_size, void* d_ws, size_t ws_size,
                              hipStream_t stream) {
    const float* ir  = (const float*)d_in[0];
    const float* ii  = (const float*)d_in[1];
    const float* yr  = (const float*)d_in[2];
    const float* yi  = (const float*)d_in[3];
    const float* inv = (const float*)d_in[4];
    const float* x1  = (const float*)d_in[5];
    const float* x2  = (const float*)d_in[6];
    float* out = (float*)d_out;

    const size_t yp_bytes = (size_t)NTILES * 16384;    // 5.13 MB (f16 frag tiles)

    // pick largest chunk count whose cand buffer fits alongside yp (slots <= 64)
    int CH = 0;
    for (int c = 32; c >= 4; c >>= 1) {
        size_t cand_bytes = (size_t)B_VOX * (2 * c) * sizeof(unsigned);
        if (ws_size >= cand_bytes + yp_bytes) { CH = c; break; }
    }

    if (CH > 0) {
        const int slots = 2 * CH;
        const int tpc   = (NTILES + CH - 1) / CH;
        unsigned* cand = (unsigned*)d_ws;
        v8h* yp = (v8h*)((char*)d_ws + (size_t)B_VOX * slots * sizeof(unsigned));

        const int units = 2 * NTILES * 512;
        split_y<<<(units + 255) / 256, 256, 0, stream>>>(yr, yi, yp);
        gemm_pre<<<dim3(B_VOX / 128, CH), 512, 0, stream>>>(ir, ii, yp, cand, tpc, slots);
        rescore_finish<<<B_VOX / 4, 256, 0, stream>>>(ir, ii, yr, yi, inv, x1, x2,
                                                      cand, slots, tpc, out);
    } else {
        int* idxo = (int*)(out + 3 * B_VOX);   // alias out row 3 (read-before-write)
        argmax_naive<<<B_VOX / 256, 256, 0, stream>>>(ir, ii, yr, yi, idxo);
        finish_k<<<B_VOX / 256, 256, 0, stream>>>(ir, ii, yr, yi,
                                                  inv, x1, x2, idxo, out);
    }
}

// Round 4
// 191.114 us; speedup vs baseline: 4.2868x; 4.2868x over previous
//
#include <hip/hip_runtime.h>
#include <hip/hip_bf16.h>
#include <stdint.h>

#define M_TIME 64
#define N_DICT 20000
#define B_VOX  8192

#define NTILES 313    // ceil(20000/64); last tile padded with zeros

typedef _Float16 v8h __attribute__((ext_vector_type(8)));   // 8 f16 (4 VGPRs)
typedef float    v4f __attribute__((ext_vector_type(4)));
typedef float    v2f __attribute__((ext_vector_type(2)));
typedef __attribute__((address_space(3))) unsigned int  lds_u32;
typedef const __attribute__((address_space(1))) unsigned int glb_u32;

__device__ __forceinline__ unsigned long long u64max(unsigned long long a, unsigned long long b) { return a > b ? a : b; }
__device__ __forceinline__ unsigned umin32(unsigned a, unsigned b) { return a < b ? a : b; }
__device__ __forceinline__ unsigned umax32(unsigned a, unsigned b) { return a > b ? a : b; }
// median of 3 == second-largest of 3: one VOP3 op (pure reg computation).
__device__ __forceinline__ unsigned umed3(unsigned a, unsigned b, unsigned c) {
    unsigned d;
    asm("v_med3_u32 %0, %1, %2, %3" : "=v"(d) : "v"(a), "v"(b), "v"(c));
    return d;
}

// ---------------------------------------------------------------------------
// Prepass: convert y to f16 ONCE, packed in A-fragment order.
// Tile T = 16 fragment-rows fr = (arr*2 + h)*4 + quad; row = 64 n x 8 f16
// (k = h*32 + quad*8 + j). 16 KB/tile.
// ---------------------------------------------------------------------------
__global__ __launch_bounds__(256) void split_y(
    const float* __restrict__ yr, const float* __restrict__ yi,
    v8h* __restrict__ yp)
{
    const int u = blockIdx.x * 256 + threadIdx.x;   // [arr][T][j(8)][n_l(64)]
    const int n_l = u & 63;
    const int j   = (u >> 6) & 7;       // fragment sub-row: k = j*8 .. j*8+7
    const int T   = (u >> 9) % NTILES;
    const int arr = u / (NTILES * 512);
    if (arr > 1) return;
    const float* P = arr ? yi : yr;
    const int n_g = T * 64 + n_l;
    v8h V;
#pragma unroll
    for (int c = 0; c < 8; ++c) {
        float v = 0.f;
        if (n_g < N_DICT) v = P[(j * 8 + c) * N_DICT + n_g];
        V[c] = (_Float16)v;
    }
    const int fr = (arr * 2 + (j >> 2)) * 4 + (j & 3);   // h = j>>2, quad = j&3
    yp[((size_t)T * 16 + fr) * 64 + n_l] = V;
}

// ---------------------------------------------------------------------------
// R20: fp32 transposed dictionary yt[n][m] = {yr[m][n], yi[m][n]}.
// Rescore then reads 512 contiguous B (8 lines) per candidate instead of
// gathering 128 scattered 64B lines across two 80 KB-stride column walks
// (~2 GB L2 line traffic -> ~60 us; that is the hidden ~85 us kernel).
// May run AFTER gemm_pre and overwrite the then-dead yp region (mode 2).
// ---------------------------------------------------------------------------
__global__ __launch_bounds__(256) void trans_y(
    const float* __restrict__ yr, const float* __restrict__ yi,
    float2* __restrict__ yt)
{
    __shared__ float tr[64][65];
    __shared__ float ti[64][65];
    const int t  = threadIdx.x;
    const int n0 = blockIdx.x * 64;
    const int nl = t & 63;
    const int mg = t >> 6;                    // 0..3 (16 m-rows each)
    const bool inb = (n0 + nl) < N_DICT;
#pragma unroll
    for (int i = 0; i < 16; ++i) {
        const int m = mg * 16 + i;
        tr[m][nl] = inb ? yr[m * N_DICT + n0 + nl] : 0.f;
        ti[m][nl] = inb ? yi[m * N_DICT + n0 + nl] : 0.f;
    }
    __syncthreads();
    const int nw = t >> 2;                    // 0..63
    const int j  = t & 3;                     // 0..3 (16 m each)
    if (n0 + nw < N_DICT) {
        float4* dst = (float4*)(yt + (size_t)(n0 + nw) * 64);
#pragma unroll
        for (int k = 0; k < 8; ++k) {
            const int m = j * 16 + 2 * k;
            float4 w;
            w.x = tr[m][nw];     w.y = ti[m][nw];
            w.z = tr[m + 1][nw]; w.w = ti[m + 1][nw];
            dst[j * 8 + k] = w;               // element pair m/2
        }
    }
}

// ---------------------------------------------------------------------------
// Phase A: f16 1-term MFMA GEMM + per-chunk top-2 (u32 packed comparator).
// R17: packed-f32 sim + v_med3_u32 second-best (~4.5 VALU/elem).
// R20: xm aliased into ys4 (xm only used after the loop, behind a
// __syncthreads) -> LDS_Block_Size 33280 -> 32768 B -> 5 blocks/CU
// (163840/32768 = 5) vs measured 3. Occupancy was the gap: MFMA roofline
// 41 us, VALU ~47 us busy, measured 95 us at 37% occupancy.
// R18 counted-vmcnt ring REVERTED (occupancy loss); R19 512-thr REVERTED
// (launch_bounds(512,8) = 64-reg unified budget < 56 arch + 16 acc need
// -> spill catastrophe, 3.2 GB scratch traffic, 727 us).
// ---------------------------------------------------------------------------
__global__ __launch_bounds__(256, 2) void gemm_pre(
    const float* __restrict__ ir, const float* __restrict__ ii,
    const v8h* __restrict__ yp,
    unsigned* __restrict__ cand, int tpc, int slots)
{
    __shared__ float4 ys4[2][1024];         // 2 x 16 KB ping-pong (32 KB exact)
    // xm[wb][bt][col][a1,a2] reuses ys4 storage after the main loop
    // (separated by __syncthreads; no DMA outstanding after last tile).
    unsigned (*xm)[2][16][2] = (unsigned (*)[2][16][2])&ys4[0][0];

    const int tid  = threadIdx.x;
    const int wave = tid >> 6, lane = tid & 63;
    const int quad = lane >> 4, col = lane & 15;
    const int wb   = wave >> 1, wn = wave & 1;
    const int vox_w = blockIdx.x * 64 + wb * 32;
    const int chunk = blockIdx.y;
    const int T0 = chunk * tpc;
    const int T1 = (T0 + tpc < NTILES) ? T0 + tpc : NTILES;

    auto dma_tile = [&](int T, int buf) {
        const float4* src = (const float4*)((const char*)yp + (size_t)T * 16384);
#pragma unroll
        for (int p = 0; p < 4; ++p) {
            const int base = p * 256 + wave * 64;            // wave-uniform
            __builtin_amdgcn_global_load_lds(
                (glb_u32*)(src + base + lane),
                (lds_u32*)(&ys4[buf][base]), 16, 0, 0);
        }
    };

    // ---- prologue: DMA tile T0 into buffer 0 ----
    dma_tile(T0, 0);

    // ---- persistent input B-frags: [arr][bt][h] single f16 (RNE) ----
    v8h fh[2][2][2];
#pragma unroll
    for (int arr = 0; arr < 2; ++arr) {
        const float* P = arr ? ii : ir;
#pragma unroll
        for (int bt = 0; bt < 2; ++bt) {
            const int b = vox_w + bt * 16 + col;
#pragma unroll
            for (int h = 0; h < 2; ++h) {
                v8h H;
#pragma unroll
                for (int j = 0; j < 8; ++j) {
                    const int k = h * 32 + quad * 8 + j;
                    H[j] = (_Float16)P[k * B_VOX + b];
                }
                fh[arr][bt][h] = H;
            }
        }
    }

    const v4f zc = {0.f, 0.f, 0.f, 0.f};
    unsigned t2a[2] = {0u, 0u}, t2b[2] = {0u, 0u};

    for (int T = T0; T < T1; ++T) {
        const int par = (T - T0) & 1;
        __syncthreads();   // drains DMA(T) into buf[par]; buf[par^1] now free
        if (T + 1 < T1) dma_tile(T + 1, par ^ 1);
        const v8h* yv = (const v8h*)ys4[par];

        v4f acc[2][2][4];                       // [bt][nt][rr,ri,s1,s2]
#pragma unroll
        for (int h = 0; h < 2; ++h) {
#pragma unroll
            for (int nt = 0; nt < 2; ++nt) {
                const int nrow = (wn * 2 + nt) * 16 + col;
                const v8h yfr = yv[((0 * 2 + h) * 4 + quad) * 64 + nrow];  // yr frag
                const v8h yfi = yv[((1 * 2 + h) * 4 + quad) * 64 + nrow];  // yi frag
#pragma unroll
                for (int bt = 0; bt < 2; ++bt) {
#define MF(A, B, C) __builtin_amdgcn_mfma_f32_16x16x32_f16(A, B, C, 0, 0, 0)
                    if (h == 0) {               // first k-half: C = zero (no init movs)
                        acc[bt][nt][0] = MF(yfr, fh[0][bt][0], zc);
                        acc[bt][nt][1] = MF(yfi, fh[0][bt][0], zc);
                        acc[bt][nt][2] = MF(yfr, fh[1][bt][0], zc);
                        acc[bt][nt][3] = MF(yfi, fh[1][bt][0], zc);
                    } else {
                        acc[bt][nt][0] = MF(yfr, fh[0][bt][1], acc[bt][nt][0]);
                        acc[bt][nt][1] = MF(yfi, fh[0][bt][1], acc[bt][nt][1]);
                        acc[bt][nt][2] = MF(yfr, fh[1][bt][1], acc[bt][nt][2]);
                        acc[bt][nt][3] = MF(yfi, fh[1][bt][1], acc[bt][nt][3]);
                    }
#undef MF
                }
            }
        }

        // ---- sim + top-2: packed-f32 sim, med3 second-best ----
        const int tl = T - T0;
#pragma unroll
        for (int nt = 0; nt < 2; ++nt) {
            const unsigned base = 0x1FFFu
                - (unsigned)(tl * 64 + (wn * 2 + nt) * 16 + quad * 4);
            v2f s01[2], s23[2];
#pragma unroll
            for (int bt = 0; bt < 2; ++bt) {
                const v4f a0 = acc[bt][nt][0], a1 = acc[bt][nt][1];
                const v4f a2 = acc[bt][nt][2], a3 = acc[bt][nt][3];
                {
                    const v2f p0 = __builtin_shufflevector(a0, a0, 0, 1);
                    const v2f p1 = __builtin_shufflevector(a1, a1, 0, 1);
                    const v2f p2 = __builtin_shufflevector(a2, a2, 0, 1);
                    const v2f p3 = __builtin_shufflevector(a3, a3, 0, 1);
                    v2f s = p0 * p0;
                    s = __builtin_elementwise_fma(p1, p1, s);
                    s = __builtin_elementwise_fma(p2, p2, s);
                    s = __builtin_elementwise_fma(p3, p3, s);
                    s01[bt] = s;
                }
                {
                    const v2f p0 = __builtin_shufflevector(a0, a0, 2, 3);
                    const v2f p1 = __builtin_shufflevector(a1, a1, 2, 3);
                    const v2f p2 = __builtin_shufflevector(a2, a2, 2, 3);
                    const v2f p3 = __builtin_shufflevector(a3, a3, 2, 3);
                    v2f s = p0 * p0;
                    s = __builtin_elementwise_fma(p1, p1, s);
                    s = __builtin_elementwise_fma(p2, p2, s);
                    s = __builtin_elementwise_fma(p3, p3, s);
                    s23[bt] = s;
                }
            }
#pragma unroll
            for (int r = 0; r < 4; ++r) {
#pragma unroll
                for (int bt = 0; bt < 2; ++bt) {     // two bt chains interleave
                    const float s = (r < 2) ? s01[bt][r] : s23[bt][r - 2];
                    const unsigned pb = (__float_as_uint(s) & 0xFFFFE000u)
                                      | (base - (unsigned)r);
                    const unsigned nb = umed3(pb, t2a[bt], t2b[bt]);  // 2nd-best
                    t2a[bt] = umax32(pb, t2a[bt]);
                    t2b[bt] = nb;
                }
            }
        }
    }

    // ---- cross-lane top-2 merge over quads (lanes c, c+16, c+32, c+48) ----
    unsigned fa1[2], fa2[2];
#pragma unroll
    for (int bt = 0; bt < 2; ++bt) {
        unsigned a1 = t2a[bt], a2 = t2b[bt];
#pragma unroll
        for (int d = 16; d <= 32; d <<= 1) {
            unsigned b1 = (unsigned)__shfl_xor((int)a1, d, 64);
            unsigned b2 = (unsigned)__shfl_xor((int)a2, d, 64);
            unsigned mn = umin32(a1, b1);
            a1 = umax32(a1, b1);
            a2 = umax32(mn, umax32(a2, b2));
        }
        fa1[bt] = a1; fa2[bt] = a2;
    }
    // ---- cross-wave (wn) merge via xm (aliased into ys4; loop is done) ----
    __syncthreads();
    if (wn == 1 && lane < 16) {
#pragma unroll
        for (int bt = 0; bt < 2; ++bt) { xm[wb][bt][lane][0] = fa1[bt]; xm[wb][bt][lane][1] = fa2[bt]; }
    }
    __syncthreads();
    if (wn == 0 && lane < 16) {
#pragma unroll
        for (int bt = 0; bt < 2; ++bt) {
            unsigned b1 = xm[wb][bt][lane][0];
            unsigned b2 = xm[wb][bt][lane][1];
            unsigned m1 = umax32(fa1[bt], b1);
            unsigned m2 = umax32(umin32(fa1[bt], b1), umax32(fa2[bt], b2));
            const size_t vox = vox_w + bt * 16 + lane;
            cand[vox * slots + chunk * 2 + 0] = m1;
            cand[vox * slots + chunk * 2 + 1] = m2;
        }
    }
}

// ---------------------------------------------------------------------------
// Phase B (fused): exact fp32 rescore of candidates within 3% of approx max,
// winner lane computes scales and writes the 4 output rows directly.
// One wave per voxel. yt path: 8 contiguous lines per candidate.
// ---------------------------------------------------------------------------
__global__ __launch_bounds__(256) void rescore_finish(
    const float* __restrict__ ir, const float* __restrict__ ii,
    const float* __restrict__ yr, const float* __restrict__ yi,
    const float2* __restrict__ yt,
    const float* __restrict__ inv, const float* __restrict__ x1,
    const float* __restrict__ x2,
    const unsigned* __restrict__ cand, int slots, int tpc,
    float* __restrict__ out)
{
    const int tid  = threadIdx.x;
    const int vox  = blockIdx.x * 4 + (tid >> 6);
    const int slot = tid & 63;

    unsigned p = (slot < slots) ? cand[(size_t)vox * slots + slot] : 0u;
    float sa = __uint_as_float(p & 0xFFFFE000u);
    const int chunkc = slot >> 1;
    const int nn = chunkc * tpc * 64 + (0x1FFF - (int)(p & 0x1FFFu));

    float amax = sa;
#pragma unroll
    for (int d = 1; d <= 32; d <<= 1) amax = fmaxf(amax, __shfl_xor(amax, d, 64));

    unsigned long long q = 0ull;
    float rr = 0.f, ri = 0.f, s1 = 0.f, s2 = 0.f;
    const bool active = (slot < slots) && (nn >= 0) && (nn < N_DICT)
                     && (sa >= 0.97f * amax);    // margin covers 1-term f16 error
    if (active) {
        if (yt) {
            const float4* yc = (const float4*)(yt + (size_t)nn * 64);
            for (int m2 = 0; m2 < 32; ++m2) {
                const float4 w = yc[m2];               // {yr,yi}[2m], {yr,yi}[2m+1]
                const int m = 2 * m2;
                float vr0 = ir[m * B_VOX + vox],       vi0 = ii[m * B_VOX + vox];
                float vr1 = ir[(m + 1) * B_VOX + vox], vi1 = ii[(m + 1) * B_VOX + vox];
                rr = fmaf(vr0, w.x, rr); ri = fmaf(vr0, w.y, ri);
                s1 = fmaf(vi0, w.x, s1); s2 = fmaf(vi0, w.y, s2);
                rr = fmaf(vr1, w.z, rr); ri = fmaf(vr1, w.w, ri);
                s1 = fmaf(vi1, w.z, s1); s2 = fmaf(vi1, w.w, s2);
            }
        } else {
            for (int m = 0; m < M_TIME; ++m) {
                float a  = yr[(size_t)m * N_DICT + nn];
                float c  = yi[(size_t)m * N_DICT + nn];
                float vr = ir[m * B_VOX + vox];
                float vi = ii[m * B_VOX + vox];
                rr = fmaf(vr, a, rr); ri = fmaf(vr, c, ri);
                s1 = fmaf(vi, a, s1); s2 = fmaf(vi, c, s2);
            }
        }
        float s = fmaf(rr, rr, fmaf(ri, ri, fmaf(s1, s1, s2 * s2)));
        q = (((unsigned long long)__float_as_uint(s)) << 32)
          | (unsigned long long)(0xFFFFFFFFu - (unsigned)nn);  // ties -> smaller n
    }
    unsigned long long qm = q;
#pragma unroll
    for (int d = 1; d <= 32; d <<= 1) qm = u64max(qm, __shfl_xor(qm, d, 64));

    if (active && q == qm && qm != 0ull) {       // exactly one lane (n in key)
        float ss = inv[nn];
        out[0 * B_VOX + vox] = (rr + s2) * ss;   // sum(yr*ir + yi*ii) * inv
        out[1 * B_VOX + vox] = (s1 - ri) * ss;   // sum(yr*ii - yi*ir) * inv
        out[2 * B_VOX + vox] = x1[nn];
        out[3 * B_VOX + vox] = x2[nn];
    }
}

// ---------------------------------------------------------------------------
// Last-resort fallbacks (tiny ws): fp32 brute-force argmax + finish.
// ---------------------------------------------------------------------------
__global__ __launch_bounds__(256, 3) void argmax_naive(
    const float* __restrict__ ir, const float* __restrict__ ii,
    const float* __restrict__ yr, const float* __restrict__ yi,
    int* __restrict__ idxout)
{
    int b = blockIdx.x * 256 + threadIdx.x;
    float bs = -1.0f; int bn = 0;
    for (int n = 0; n < N_DICT; ++n) {
        float a_rr = 0.f, a_ri = 0.f, a_s1 = 0.f, a_s2 = 0.f;
        for (int m = 0; m < M_TIME; ++m) {
            float a = yr[m * N_DICT + n], c = yi[m * N_DICT + n];
            float vr = ir[m * B_VOX + b], vi = ii[m * B_VOX + b];
            a_rr = fmaf(vr, a, a_rr); a_ri = fmaf(vr, c, a_ri);
            a_s1 = fmaf(vi, a, a_s1); a_s2 = fmaf(vi, c, a_s2);
        }
        float sim = fmaf(a_rr, a_rr, fmaf(a_ri, a_ri, fmaf(a_s1, a_s1, a_s2 * a_s2)));
        if (sim > bs) { bs = sim; bn = n; }
    }
    idxout[b] = bn;
}

__global__ void finish_k(const float* __restrict__ ir, const float* __restrict__ ii,
                         const float* __restrict__ yr, const float* __restrict__ yi,
                         const float* __restrict__ inv, const float* __restrict__ x1,
                         const float* __restrict__ x2,
                         const int* __restrict__ idxin, float* __restrict__ out)
{
    int b = blockIdx.x * blockDim.x + threadIdx.x;
    int idx = idxin[b];
    float ar = 0.f, ai = 0.f;
    for (int m = 0; m < M_TIME; ++m) {
        float a  = yr[(size_t)m * N_DICT + idx];
        float c  = yi[(size_t)m * N_DICT + idx];
        float vr = ir[m * B_VOX + b];
        float vi = ii[m * B_VOX + b];
        ar = fmaf(a, vr, ar); ar = fmaf(c, vi, ar);
        ai = fmaf(a, vi, ai); ai = fmaf(-c, vr, ai);
    }
    float s = inv[idx];
    out[0 * B_VOX + b] = ar * s;
    out[1 * B_VOX + b] = ai * s;
    out[2 * B_VOX + b] = x1[idx];
    out[3 * B_VOX + b] = x2[idx];
}

extern "C" void kernel_launch(void* const* d_in, const int* in_sizes, int n_in,
                              void* d_out, int out_size, void* d_ws, size_t ws_size,
                              hipStream_t stream) {
    const float* ir  = (const float*)d_in[0];
    const float* ii  = (const float*)d_in[1];
    const float* yr  = (const float*)d_in[2];
    const float* yi  = (const float*)d_in[3];
    const float* inv = (const float*)d_in[4];
    const float* x1  = (const float*)d_in[5];
    const float* x2  = (const float*)d_in[6];
    float* out = (float*)d_out;

    const size_t yp_bytes = (size_t)NTILES * 16384;               // 5.13 MB
    const size_t yt_bytes = (size_t)N_DICT * 64 * sizeof(float2); // 10.24 MB
    const size_t ov_bytes = yt_bytes > yp_bytes ? yt_bytes : yp_bytes;

    // mode 1: cand | yp | yt   (trans_y any time)      needs cand+15.4 MB
    // mode 2: cand | (yp/yt overlapped)                needs cand+10.24 MB
    //         (trans_y runs AFTER gemm_pre; yp dead by then)
    // mode 0: cand | yp        (no yt; column-gather rescore)
    int CH = 0, mode = -1;
    for (int c = 32; c >= 4 && CH == 0; c >>= 1) {
        size_t cb = (size_t)B_VOX * (2 * c) * sizeof(unsigned);
        if (ws_size >= cb + yp_bytes + yt_bytes) { CH = c; mode = 1; }
    }
    for (int c = 32; c >= 4 && CH == 0; c >>= 1) {
        size_t cb = (size_t)B_VOX * (2 * c) * sizeof(unsigned);
        if (ws_size >= cb + ov_bytes) { CH = c; mode = 2; }
    }
    for (int c = 32; c >= 4 && CH == 0; c >>= 1) {
        size_t cb = (size_t)B_VOX * (2 * c) * sizeof(unsigned);
        if (ws_size >= cb + yp_bytes) { CH = c; mode = 0; }
    }

    if (CH > 0) {
        const int slots = 2 * CH;
        const int tpc   = (NTILES + CH - 1) / CH;
        unsigned* cand = (unsigned*)d_ws;
        char* base = (char*)d_ws + (size_t)B_VOX * slots * sizeof(unsigned);
        v8h*    yp = (v8h*)base;
        float2* yt = nullptr;
        if (mode == 1) yt = (float2*)(base + yp_bytes);
        if (mode == 2) yt = (float2*)base;             // overwrites yp post-gemm

        const int units = 2 * NTILES * 512;
        split_y<<<(units + 255) / 256, 256, 0, stream>>>(yr, yi, yp);
        if (mode == 1) trans_y<<<NTILES, 256, 0, stream>>>(yr, yi, yt);
        gemm_pre<<<dim3(B_VOX / 64, CH), 256, 0, stream>>>(ir, ii, yp, cand, tpc, slots);
        if (mode == 2) trans_y<<<NTILES, 256, 0, stream>>>(yr, yi, yt);
        rescore_finish<<<B_VOX / 4, 256, 0, stream>>>(ir, ii, yr, yi, yt, inv, x1, x2,
                                                      cand, slots, tpc, out);
    } else {
        int* idxo = (int*)(out + 3 * B_VOX);   // alias out row 3 (read-before-write)
        argmax_naive<<<B_VOX / 256, 256, 0, stream>>>(ir, ii, yr, yi, idxo);
        finish_k<<<B_VOX / 256, 256, 0, stream>>>(ir, ii, yr, yi,
                                                  inv, x1, x2, idxo, out);
    }
}

// Round 5
// 188.074 us; speedup vs baseline: 4.3561x; 1.0162x over previous
//
#include <hip/hip_runtime.h>
#include <hip/hip_bf16.h>
#include <stdint.h>

#define M_TIME 64
#define N_DICT 20000
#define B_VOX  8192

#define NTILES 313    // ceil(20000/64); last tile padded with zeros

typedef _Float16 v8h __attribute__((ext_vector_type(8)));   // 8 f16 (4 VGPRs)
typedef float    v4f __attribute__((ext_vector_type(4)));
typedef float    v2f __attribute__((ext_vector_type(2)));

__device__ __forceinline__ unsigned long long u64max(unsigned long long a, unsigned long long b) { return a > b ? a : b; }
__device__ __forceinline__ unsigned umin32(unsigned a, unsigned b) { return a < b ? a : b; }
__device__ __forceinline__ unsigned umax32(unsigned a, unsigned b) { return a > b ? a : b; }
// median of 3 == second-largest of 3: one VOP3 op (pure reg computation).
__device__ __forceinline__ unsigned umed3(unsigned a, unsigned b, unsigned c) {
    unsigned d;
    asm("v_med3_u32 %0, %1, %2, %3" : "=v"(d) : "v"(a), "v"(b), "v"(c));
    return d;
}

// ---------------------------------------------------------------------------
// Prepass: convert y to f16 ONCE, packed in A-fragment order.
// Tile T = 16 fragment-rows fr = (arr*2 + h)*4 + quad; row = 64 n x 8 f16
// (k = h*32 + quad*8 + j). 16 KB/tile.
// ---------------------------------------------------------------------------
__global__ __launch_bounds__(256) void split_y(
    const float* __restrict__ yr, const float* __restrict__ yi,
    v8h* __restrict__ yp)
{
    const int u = blockIdx.x * 256 + threadIdx.x;   // [arr][T][j(8)][n_l(64)]
    const int n_l = u & 63;
    const int j   = (u >> 6) & 7;       // fragment sub-row: k = j*8 .. j*8+7
    const int T   = (u >> 9) % NTILES;
    const int arr = u / (NTILES * 512);
    if (arr > 1) return;
    const float* P = arr ? yi : yr;
    const int n_g = T * 64 + n_l;
    v8h V;
#pragma unroll
    for (int c = 0; c < 8; ++c) {
        float v = 0.f;
        if (n_g < N_DICT) v = P[(j * 8 + c) * N_DICT + n_g];
        V[c] = (_Float16)v;
    }
    const int fr = (arr * 2 + (j >> 2)) * 4 + (j & 3);   // h = j>>2, quad = j&3
    yp[((size_t)T * 16 + fr) * 64 + n_l] = V;
}

// ---------------------------------------------------------------------------
// Phase A: f16 1-term MFMA GEMM + per-chunk top-2 (u32 packed comparator).
// R17: packed-f32 sim + v_med3_u32 second-best (~4.5 VALU/elem).
// R21: LDS staging DELETED (Common-mistake #7). yp's per-chunk working set
// is 160 KB -> permanently L2-hot (each tile re-read by 128 blocks), and
// within a block only 2 waves shared each fragment. Fragments now load
// directly global->VGPR (8 x dwordx4 per tile per wave); NO barrier in the
// main loop -> the per-tile vmcnt(0)+syncthreads drain (the measured 2.3x
// gap to the 40.5 us MFMA roofline at 12 waves/CU) is structurally gone.
// Loads for tile T+1 issue between MFMA(T) and epilogue(T): ~200 cyc of
// comparator VALU runs under the L2 latency. LDS = 512 B (xm only).
// History: R18 counted-vmcnt ring REVERTED (LDS 48KB cost occupancy);
// R19 512-thr REVERTED (launch_bounds(512,8)=64-reg budget -> spill, 727us);
// R20 xm-alias kept LDS at 32KB but occupancy never moved (not LDS-bound).
// ---------------------------------------------------------------------------
__global__ __launch_bounds__(256, 2) void gemm_pre(
    const float* __restrict__ ir, const float* __restrict__ ii,
    const v8h* __restrict__ yp,
    unsigned* __restrict__ cand, int tpc, int slots)
{
    __shared__ unsigned xm[2][2][16][2];    // [wb][bt][col][a1,a2]  (512 B)

    const int tid  = threadIdx.x;
    const int wave = tid >> 6, lane = tid & 63;
    const int quad = lane >> 4, col = lane & 15;
    const int wb   = wave >> 1, wn = wave & 1;
    const int vox_w = blockIdx.x * 64 + wb * 32;
    const int chunk = blockIdx.y;
    const int T0 = chunk * tpc;
    const int T1 = (T0 + tpc < NTILES) ? T0 + tpc : NTILES;

    // ---- persistent input B-frags: [arr][bt][h] single f16 (RNE) ----
    v8h fh[2][2][2];
#pragma unroll
    for (int arr = 0; arr < 2; ++arr) {
        const float* P = arr ? ii : ir;
#pragma unroll
        for (int bt = 0; bt < 2; ++bt) {
            const int b = vox_w + bt * 16 + col;
#pragma unroll
            for (int h = 0; h < 2; ++h) {
                v8h H;
#pragma unroll
                for (int j = 0; j < 8; ++j) {
                    const int k = h * 32 + quad * 8 + j;
                    H[j] = (_Float16)P[k * B_VOX + b];
                }
                fh[arr][bt][h] = H;
            }
        }
    }

    // ---- y A-frags for the current tile, in registers ----
    v8h yfr[2][2], yfi[2][2];               // [h][nt]
    auto loadf = [&](int T) {
        const v8h* yv = (const v8h*)((const char*)yp + (size_t)T * 16384);
#pragma unroll
        for (int h = 0; h < 2; ++h)
#pragma unroll
            for (int nt = 0; nt < 2; ++nt) {
                const int nrow = (wn * 2 + nt) * 16 + col;
                yfr[h][nt] = yv[((0 * 2 + h) * 4 + quad) * 64 + nrow];
                yfi[h][nt] = yv[((1 * 2 + h) * 4 + quad) * 64 + nrow];
            }
    };

    const v4f zc = {0.f, 0.f, 0.f, 0.f};
    unsigned t2a[2] = {0u, 0u}, t2b[2] = {0u, 0u};

    loadf(T0);
    for (int T = T0; T < T1; ++T) {
        v4f acc[2][2][4];                       // [bt][nt][rr,ri,s1,s2]
#pragma unroll
        for (int h = 0; h < 2; ++h) {
#pragma unroll
            for (int nt = 0; nt < 2; ++nt) {
#pragma unroll
                for (int bt = 0; bt < 2; ++bt) {
#define MF(A, B, C) __builtin_amdgcn_mfma_f32_16x16x32_f16(A, B, C, 0, 0, 0)
                    if (h == 0) {               // first k-half: C = zero (no init movs)
                        acc[bt][nt][0] = MF(yfr[0][nt], fh[0][bt][0], zc);
                        acc[bt][nt][1] = MF(yfi[0][nt], fh[0][bt][0], zc);
                        acc[bt][nt][2] = MF(yfr[0][nt], fh[1][bt][0], zc);
                        acc[bt][nt][3] = MF(yfi[0][nt], fh[1][bt][0], zc);
                    } else {
                        acc[bt][nt][0] = MF(yfr[1][nt], fh[0][bt][1], acc[bt][nt][0]);
                        acc[bt][nt][1] = MF(yfi[1][nt], fh[0][bt][1], acc[bt][nt][1]);
                        acc[bt][nt][2] = MF(yfr[1][nt], fh[1][bt][1], acc[bt][nt][2]);
                        acc[bt][nt][3] = MF(yfi[1][nt], fh[1][bt][1], acc[bt][nt][3]);
                    }
#undef MF
                }
            }
        }

        // frags(T) are dead; issue loads for T+1 now so the epilogue VALU
        // below runs under their L1/L2 latency (no barrier, pure reg deps).
        if (T + 1 < T1) loadf(T + 1);

        // ---- sim + top-2: packed-f32 sim, med3 second-best ----
        const int tl = T - T0;
#pragma unroll
        for (int nt = 0; nt < 2; ++nt) {
            const unsigned base = 0x1FFFu
                - (unsigned)(tl * 64 + (wn * 2 + nt) * 16 + quad * 4);
            v2f s01[2], s23[2];
#pragma unroll
            for (int bt = 0; bt < 2; ++bt) {
                const v4f a0 = acc[bt][nt][0], a1 = acc[bt][nt][1];
                const v4f a2 = acc[bt][nt][2], a3 = acc[bt][nt][3];
                {
                    const v2f p0 = __builtin_shufflevector(a0, a0, 0, 1);
                    const v2f p1 = __builtin_shufflevector(a1, a1, 0, 1);
                    const v2f p2 = __builtin_shufflevector(a2, a2, 0, 1);
                    const v2f p3 = __builtin_shufflevector(a3, a3, 0, 1);
                    v2f s = p0 * p0;
                    s = __builtin_elementwise_fma(p1, p1, s);
                    s = __builtin_elementwise_fma(p2, p2, s);
                    s = __builtin_elementwise_fma(p3, p3, s);
                    s01[bt] = s;
                }
                {
                    const v2f p0 = __builtin_shufflevector(a0, a0, 2, 3);
                    const v2f p1 = __builtin_shufflevector(a1, a1, 2, 3);
                    const v2f p2 = __builtin_shufflevector(a2, a2, 2, 3);
                    const v2f p3 = __builtin_shufflevector(a3, a3, 2, 3);
                    v2f s = p0 * p0;
                    s = __builtin_elementwise_fma(p1, p1, s);
                    s = __builtin_elementwise_fma(p2, p2, s);
                    s = __builtin_elementwise_fma(p3, p3, s);
                    s23[bt] = s;
                }
            }
#pragma unroll
            for (int r = 0; r < 4; ++r) {
#pragma unroll
                for (int bt = 0; bt < 2; ++bt) {     // two bt chains interleave
                    const float s = (r < 2) ? s01[bt][r] : s23[bt][r - 2];
                    const unsigned pb = (__float_as_uint(s) & 0xFFFFE000u)
                                      | (base - (unsigned)r);
                    const unsigned nb = umed3(pb, t2a[bt], t2b[bt]);  // 2nd-best
                    t2a[bt] = umax32(pb, t2a[bt]);
                    t2b[bt] = nb;
                }
            }
        }
    }

    // ---- cross-lane top-2 merge over quads (lanes c, c+16, c+32, c+48) ----
    unsigned fa1[2], fa2[2];
#pragma unroll
    for (int bt = 0; bt < 2; ++bt) {
        unsigned a1 = t2a[bt], a2 = t2b[bt];
#pragma unroll
        for (int d = 16; d <= 32; d <<= 1) {
            unsigned b1 = (unsigned)__shfl_xor((int)a1, d, 64);
            unsigned b2 = (unsigned)__shfl_xor((int)a2, d, 64);
            unsigned mn = umin32(a1, b1);
            a1 = umax32(a1, b1);
            a2 = umax32(mn, umax32(a2, b2));
        }
        fa1[bt] = a1; fa2[bt] = a2;
    }
    // ---- cross-wave (wn) merge: wn==1 publishes, wn==0 writes ----
    __syncthreads();
    if (wn == 1 && lane < 16) {
#pragma unroll
        for (int bt = 0; bt < 2; ++bt) { xm[wb][bt][lane][0] = fa1[bt]; xm[wb][bt][lane][1] = fa2[bt]; }
    }
    __syncthreads();
    if (wn == 0 && lane < 16) {
#pragma unroll
        for (int bt = 0; bt < 2; ++bt) {
            unsigned b1 = xm[wb][bt][lane][0];
            unsigned b2 = xm[wb][bt][lane][1];
            unsigned m1 = umax32(fa1[bt], b1);
            unsigned m2 = umax32(umin32(fa1[bt], b1), umax32(fa2[bt], b2));
            const size_t vox = vox_w + bt * 16 + lane;
            cand[vox * slots + chunk * 2 + 0] = m1;
            cand[vox * slots + chunk * 2 + 1] = m2;
        }
    }
}

// ---------------------------------------------------------------------------
// Phase B (fused): exact fp32 rescore of candidates within 3% of approx max,
// winner lane computes scales and writes the 4 output rows directly.
// One wave per voxel.
// ---------------------------------------------------------------------------
__global__ __launch_bounds__(256) void rescore_finish(
    const float* __restrict__ ir, const float* __restrict__ ii,
    const float* __restrict__ yr, const float* __restrict__ yi,
    const float* __restrict__ inv, const float* __restrict__ x1,
    const float* __restrict__ x2,
    const unsigned* __restrict__ cand, int slots, int tpc,
    float* __restrict__ out)
{
    const int tid  = threadIdx.x;
    const int vox  = blockIdx.x * 4 + (tid >> 6);
    const int slot = tid & 63;

    unsigned p = (slot < slots) ? cand[(size_t)vox * slots + slot] : 0u;
    float sa = __uint_as_float(p & 0xFFFFE000u);
    const int chunkc = slot >> 1;
    const int nn = chunkc * tpc * 64 + (0x1FFF - (int)(p & 0x1FFFu));

    float amax = sa;
#pragma unroll
    for (int d = 1; d <= 32; d <<= 1) amax = fmaxf(amax, __shfl_xor(amax, d, 64));

    unsigned long long q = 0ull;
    float rr = 0.f, ri = 0.f, s1 = 0.f, s2 = 0.f;
    const bool active = (slot < slots) && (nn >= 0) && (nn < N_DICT)
                     && (sa >= 0.97f * amax);    // margin covers 1-term f16 error
    if (active) {
        for (int m = 0; m < M_TIME; ++m) {
            float a  = yr[(size_t)m * N_DICT + nn];
            float c  = yi[(size_t)m * N_DICT + nn];
            float vr = ir[m * B_VOX + vox];
            float vi = ii[m * B_VOX + vox];
            rr = fmaf(vr, a, rr); ri = fmaf(vr, c, ri);
            s1 = fmaf(vi, a, s1); s2 = fmaf(vi, c, s2);
        }
        float s = fmaf(rr, rr, fmaf(ri, ri, fmaf(s1, s1, s2 * s2)));
        q = (((unsigned long long)__float_as_uint(s)) << 32)
          | (unsigned long long)(0xFFFFFFFFu - (unsigned)nn);  // ties -> smaller n
    }
    unsigned long long qm = q;
#pragma unroll
    for (int d = 1; d <= 32; d <<= 1) qm = u64max(qm, __shfl_xor(qm, d, 64));

    if (active && q == qm && qm != 0ull) {       // exactly one lane (n in key)
        float ss = inv[nn];
        out[0 * B_VOX + vox] = (rr + s2) * ss;   // sum(yr*ir + yi*ii) * inv
        out[1 * B_VOX + vox] = (s1 - ri) * ss;   // sum(yr*ii - yi*ir) * inv
        out[2 * B_VOX + vox] = x1[nn];
        out[3 * B_VOX + vox] = x2[nn];
    }
}

// ---------------------------------------------------------------------------
// Last-resort fallbacks (tiny ws): fp32 brute-force argmax + finish.
// ---------------------------------------------------------------------------
__global__ __launch_bounds__(256, 3) void argmax_naive(
    const float* __restrict__ ir, const float* __restrict__ ii,
    const float* __restrict__ yr, const float* __restrict__ yi,
    int* __restrict__ idxout)
{
    int b = blockIdx.x * 256 + threadIdx.x;
    float bs = -1.0f; int bn = 0;
    for (int n = 0; n < N_DICT; ++n) {
        float a_rr = 0.f, a_ri = 0.f, a_s1 = 0.f, a_s2 = 0.f;
        for (int m = 0; m < M_TIME; ++m) {
            float a = yr[m * N_DICT + n], c = yi[m * N_DICT + n];
            float vr = ir[m * B_VOX + b], vi = ii[m * B_VOX + b];
            a_rr = fmaf(vr, a, a_rr); a_ri = fmaf(vr, c, a_ri);
            a_s1 = fmaf(vi, a, a_s1); a_s2 = fmaf(vi, c, a_s2);
        }
        float sim = fmaf(a_rr, a_rr, fmaf(a_ri, a_ri, fmaf(a_s1, a_s1, a_s2 * a_s2)));
        if (sim > bs) { bs = sim; bn = n; }
    }
    idxout[b] = bn;
}

__global__ void finish_k(const float* __restrict__ ir, const float* __restrict__ ii,
                         const float* __restrict__ yr, const float* __restrict__ yi,
                         const float* __restrict__ inv, const float* __restrict__ x1,
                         const float* __restrict__ x2,
                         const int* __restrict__ idxin, float* __restrict__ out)
{
    int b = blockIdx.x * blockDim.x + threadIdx.x;
    int idx = idxin[b];
    float ar = 0.f, ai = 0.f;
    for (int m = 0; m < M_TIME; ++m) {
        float a  = yr[(size_t)m * N_DICT + idx];
        float c  = yi[(size_t)m * N_DICT + idx];
        float vr = ir[m * B_VOX + b];
        float vi = ii[m * B_VOX + b];
        ar = fmaf(a, vr, ar); ar = fmaf(c, vi, ar);
        ai = fmaf(a, vi, ai); ai = fmaf(-c, vr, ai);
    }
    float s = inv[idx];
    out[0 * B_VOX + b] = ar * s;
    out[1 * B_VOX + b] = ai * s;
    out[2 * B_VOX + b] = x1[idx];
    out[3 * B_VOX + b] = x2[idx];
}

extern "C" void kernel_launch(void* const* d_in, const int* in_sizes, int n_in,
                              void* d_out, int out_size, void* d_ws, size_t ws_size,
                              hipStream_t stream) {
    const float* ir  = (const float*)d_in[0];
    const float* ii  = (const float*)d_in[1];
    const float* yr  = (const float*)d_in[2];
    const float* yi  = (const float*)d_in[3];
    const float* inv = (const float*)d_in[4];
    const float* x1  = (const float*)d_in[5];
    const float* x2  = (const float*)d_in[6];
    float* out = (float*)d_out;

    const size_t yp_bytes = (size_t)NTILES * 16384;    // 5.13 MB (f16 frag tiles)

    // pick largest chunk count whose cand buffer fits alongside yp (slots <= 64)
    int CH = 0;
    for (int c = 32; c >= 4; c >>= 1) {
        size_t cand_bytes = (size_t)B_VOX * (2 * c) * sizeof(unsigned);
        if (ws_size >= cand_bytes + yp_bytes) { CH = c; break; }
    }

    if (CH > 0) {
        const int slots = 2 * CH;
        const int tpc   = (NTILES + CH - 1) / CH;
        unsigned* cand = (unsigned*)d_ws;
        v8h* yp = (v8h*)((char*)d_ws + (size_t)B_VOX * slots * sizeof(unsigned));

        const int units = 2 * NTILES * 512;
        split_y<<<(units + 255) / 256, 256, 0, stream>>>(yr, yi, yp);
        gemm_pre<<<dim3(B_VOX / 64, CH), 256, 0, stream>>>(ir, ii, yp, cand, tpc, slots);
        rescore_finish<<<B_VOX / 4, 256, 0, stream>>>(ir, ii, yr, yi, inv, x1, x2,
                                                      cand, slots, tpc, out);
    } else {
        int* idxo = (int*)(out + 3 * B_VOX);   // alias out row 3 (read-before-write)
        argmax_naive<<<B_VOX / 256, 256, 0, stream>>>(ir, ii, yr, yi, idxo);
        finish_k<<<B_VOX / 256, 256, 0, stream>>>(ir, ii, yr, yi,
                                                  inv, x1, x2, idxo, out);
    }
}